// Round 1
// baseline (6602.563 us; speedup 1.0000x reference)
//
#include <hip/hip_runtime.h>

typedef __attribute__((ext_vector_type(8))) short short8;
typedef __attribute__((ext_vector_type(4))) short short4_t;
typedef __attribute__((ext_vector_type(4))) float f32x4;

#define LOG2E 1.44269504088896340736f

static __device__ __forceinline__ unsigned short f2bf(float f) {
  unsigned int u = __builtin_bit_cast(unsigned int, f);
  u += 0x7fffu + ((u >> 16) & 1u);
  return (unsigned short)(u >> 16);
}
static __device__ __forceinline__ float bf2f(unsigned short h) {
  return __builtin_bit_cast(float, ((unsigned int)h) << 16);
}
static __device__ __forceinline__ f32x4 mfma16(short8 a, short8 b, f32x4 c) {
  return __builtin_amdgcn_mfma_f32_16x16x32_bf16(a, b, c, 0, 0, 0);
}

// ---------------------------------------------------------------------------
// pack_kernel: fp32 weights -> bf16 MFMA B-fragments, gate scales (log2e /
// 2*log2e) folded in so activations become exp2/rcp only.
// pwh layout: frag tf = ((w*4+g)*2+n)*8+kk  (w=wave 0..7, g=gate, n=subtile,
//             kk=K-step), element = tf*512 + lane*8 + j ; k = 32kk+8q+j,
//             col = 256g + 32w + 16n + rr   (q=lane>>4, rr=lane&15)
// pwx layout: (ct*4+kk)*512 + lane*8 + j ; ct = abs col tile 0..63
// pwph layout: (tc*8+kk)*512 + lane*8 + j ; tc = out col tile 0..7
// ---------------------------------------------------------------------------
__global__ __launch_bounds__(256) void pack_kernel(
    const float* __restrict__ w_gx, const float* __restrict__ w_gh, const float* __restrict__ b_g,
    const float* __restrict__ w_ix, const float* __restrict__ w_ih, const float* __restrict__ b_i,
    const float* __restrict__ w_fx, const float* __restrict__ w_fh, const float* __restrict__ b_f,
    const float* __restrict__ w_ox, const float* __restrict__ w_oh, const float* __restrict__ b_o,
    const float* __restrict__ w_ph,
    short* __restrict__ pwh, short* __restrict__ pwx, short* __restrict__ pwph,
    float* __restrict__ bsc)
{
  int e = blockIdx.x * 256 + threadIdx.x;
  if (e < 262144) {
    int j = e & 7, l = (e >> 3) & 63, tf = e >> 9;
    int kk = tf & 7, n = (tf >> 3) & 1, g = (tf >> 4) & 3, w = tf >> 6;
    int q = l >> 4, rr = l & 15;
    int k = 32 * kk + 8 * q + j;
    int col = 32 * w + 16 * n + rr;
    const float* wh = (g == 0) ? w_gh : (g == 1) ? w_ih : (g == 2) ? w_fh : w_oh;
    float s = (g == 0) ? 2.0f * LOG2E : LOG2E;
    pwh[e] = (short)f2bf(wh[k * 256 + col] * s);
  } else if (e < 262144 + 131072) {
    int e2 = e - 262144;
    int j = e2 & 7, l = (e2 >> 3) & 63, kk = (e2 >> 9) & 3, ct = e2 >> 11;
    int q = l >> 4, rr = l & 15;
    int g = ct >> 4;
    int colg = (ct & 15) * 16 + rr;
    int k = 32 * kk + 8 * q + j;
    const float* wx = (g == 0) ? w_gx : (g == 1) ? w_ix : (g == 2) ? w_fx : w_ox;
    float s = (g == 0) ? 2.0f * LOG2E : LOG2E;
    pwx[e2] = (short)f2bf(wx[k * 256 + colg] * s);
  } else if (e < 262144 + 131072 + 32768) {
    int e3 = e - (262144 + 131072);
    int j = e3 & 7, l = (e3 >> 3) & 63, kk = (e3 >> 9) & 7, tc = e3 >> 12;
    int q = l >> 4, rr = l & 15;
    int k = 32 * kk + 8 * q + j;
    int col = tc * 16 + rr;
    pwph[e3] = (short)f2bf(w_ph[k * 128 + col]);
  } else if (e < 262144 + 131072 + 32768 + 1024) {
    int e4 = e - (262144 + 131072 + 32768);
    int g = e4 >> 8, c = e4 & 255;
    const float* bb = (g == 0) ? b_g : (g == 1) ? b_i : (g == 2) ? b_f : b_o;
    float s = (g == 0) ? 2.0f * LOG2E : LOG2E;
    bsc[e4] = bb[c] * s;
  }
}

// ---------------------------------------------------------------------------
// xproj_kernel: xp[t][b][:] = scale_g * (x[b,t,:] @ w_x + b), written as bf16
// C-fragments in the recurrent kernel's (gb, w, tt) tile order.
// block = 256 thr (4 waves); grid = (Tc, 8)
// ---------------------------------------------------------------------------
__global__ __launch_bounds__(256) void xproj_kernel(
    const float* __restrict__ x, const short* __restrict__ pwx,
    const float* __restrict__ bsc, short* __restrict__ xp, int t0)
{
  __shared__ short xt[2048];  // 16 x 128 bf16, XOR-swizzled rows
  int tid = threadIdx.x;
  int tloc = blockIdx.x, gb = blockIdx.y;
  int t = t0 + tloc;
  {
    int r = tid >> 4, dg = tid & 15;
    const float* src = x + ((size_t)(gb * 16 + r) * 1024 + t) * 128 + dg * 8;
    f32x4 u0 = *(const f32x4*)src;
    f32x4 u1 = *(const f32x4*)(src + 4);
    short8 v;
    v[0] = (short)f2bf(u0[0]); v[1] = (short)f2bf(u0[1]);
    v[2] = (short)f2bf(u0[2]); v[3] = (short)f2bf(u0[3]);
    v[4] = (short)f2bf(u1[0]); v[5] = (short)f2bf(u1[1]);
    v[6] = (short)f2bf(u1[2]); v[7] = (short)f2bf(u1[3]);
    *(short8*)((char*)xt + r * 256 + ((dg * 16) ^ ((r & 7) << 4))) = v;
  }
  __syncthreads();
  int wv = tid >> 6, lane = tid & 63;
  int q = lane >> 4, rr = lane & 15;
  short8 a[4];
#pragma unroll
  for (int kk = 0; kk < 4; ++kk)
    a[kk] = *(const short8*)((const char*)xt + rr * 256 + ((kk * 64 + q * 16) ^ ((rr & 7) << 4)));
#pragma unroll
  for (int i = 0; i < 16; ++i) {
    int ct = wv * 16 + i;
    float bias = bsc[ct * 16 + rr];
    f32x4 acc = {bias, bias, bias, bias};
#pragma unroll
    for (int kk = 0; kk < 4; ++kk) {
      short8 b = *(const short8*)(pwx + (size_t)(ct * 4 + kk) * 512 + lane * 8);
      acc = mfma16(a[kk], b, acc);
    }
    int wrec = (ct >> 1) & 7, tt2 = (ct >> 4) * 2 + (ct & 1);
    short4_t o;
    o[0] = (short)f2bf(acc[0]); o[1] = (short)f2bf(acc[1]);
    o[2] = (short)f2bf(acc[2]); o[3] = (short)f2bf(acc[3]);
    *(short4_t*)(xp + ((size_t)(tloc * 8 + gb) * 64 + wrec * 8 + tt2) * 256 + lane * 4) = o;
  }
}

// ---------------------------------------------------------------------------
// rec_kernel: the serial LSTM loop. grid = 8 WGs (one per 16-row batch group),
// 512 threads (8 waves). Wave w owns h-cols [32w,32w+32): tiles tt = g*2+n.
// h double-buffered in LDS (XOR swizzle), c in registers (fp32), w_h streamed
// from L2 (loop-invariant addresses), xp prefetched one step ahead.
// ---------------------------------------------------------------------------
__global__ __launch_bounds__(512) void rec_kernel(
    const short* __restrict__ pwh, const short* __restrict__ xp,
    const short* __restrict__ pwph, const float* __restrict__ b_p,
    float* __restrict__ state_c, short* __restrict__ state_h,
    float* __restrict__ out, int tlen, int first, int last)
{
  __shared__ short hbuf[2][4096];  // 2 x (16 rows x 256 cols) bf16
  int tid = threadIdx.x;
  int gb = blockIdx.x;
  int w = tid >> 6, lane = tid & 63;
  int q = lane >> 4, rr = lane & 15;
  char* hb = (char*)hbuf;

  f32x4 cst[2];
  if (first) {
    f32x4 z = {0.f, 0.f, 0.f, 0.f};
    cst[0] = z; cst[1] = z;
    short8 z8 = {0, 0, 0, 0, 0, 0, 0, 0};
    *(short8*)(hb + tid * 16) = z8;  // 512 thr x 16B = 8192B = hbuf[0]
  } else {
#pragma unroll
    for (int n = 0; n < 2; ++n) {
      cst[n] = *(const f32x4*)(state_c + ((size_t)(gb * 8 + w) * 2 + n) * 256 + lane * 4);
      short4_t hs = *(const short4_t*)(state_h + ((size_t)(gb * 8 + w) * 2 + n) * 256 + lane * 4);
#pragma unroll
      for (int r = 0; r < 4; ++r) {
        int row = q * 4 + r, col = 32 * w + 16 * n + rr;
        *(short*)(hb + row * 512 + ((col * 2) ^ ((row & 7) << 4))) = hs[r];
      }
    }
  }
  __syncthreads();

  short4_t xpc[8];
#pragma unroll
  for (int tt = 0; tt < 8; ++tt)
    xpc[tt] = *(const short4_t*)(xp + ((size_t)gb * 64 + w * 8 + tt) * 256 + lane * 4);

  unsigned par = 0;
  for (int t = 0; t < tlen; ++t) {
    // prefetch next step's xp fragments (clamped; overlaps with MFMA below)
    int tn = (t + 1 < tlen) ? (t + 1) : t;
    short4_t xpn[8];
#pragma unroll
    for (int tt = 0; tt < 8; ++tt)
      xpn[tt] = *(const short4_t*)(xp + ((size_t)(tn * 8 + gb) * 64 + w * 8 + tt) * 256 + lane * 4);

    f32x4 acc[8];
#pragma unroll
    for (int tt = 0; tt < 8; ++tt) {
      acc[tt][0] = bf2f((unsigned short)xpc[tt][0]);
      acc[tt][1] = bf2f((unsigned short)xpc[tt][1]);
      acc[tt][2] = bf2f((unsigned short)xpc[tt][2]);
      acc[tt][3] = bf2f((unsigned short)xpc[tt][3]);
    }
#pragma unroll
    for (int kk = 0; kk < 8; ++kk) {
      short8 a = *(const short8*)(hb + par * 8192 + rr * 512 + ((kk * 64 + q * 16) ^ ((rr & 7) << 4)));
#pragma unroll
      for (int tt = 0; tt < 8; ++tt) {
        short8 b = *(const short8*)(pwh + ((size_t)(w * 8 + tt) * 8 + kk) * 512 + lane * 8);
        acc[tt] = mfma16(a, b, acc[tt]);
      }
    }
#pragma unroll
    for (int n = 0; n < 2; ++n) {
      f32x4 xg = acc[0 + n], xi = acc[2 + n], xf = acc[4 + n], xo = acc[6 + n];
      f32x4 cc = cst[n];
      f32x4 hh;
#pragma unroll
      for (int r = 0; r < 4; ++r) {
        float gg = 2.0f * __builtin_amdgcn_rcpf(1.0f + __builtin_amdgcn_exp2f(-xg[r])) - 1.0f;
        float ii = __builtin_amdgcn_rcpf(1.0f + __builtin_amdgcn_exp2f(-xi[r]));
        float ff = __builtin_amdgcn_rcpf(1.0f + __builtin_amdgcn_exp2f(-xf[r]));
        float oo = __builtin_amdgcn_rcpf(1.0f + __builtin_amdgcn_exp2f(-xo[r]));
        float c2 = gg * ii + cc[r] * ff;
        float th = 2.0f * __builtin_amdgcn_rcpf(1.0f + __builtin_amdgcn_exp2f(-2.0f * LOG2E * c2)) - 1.0f;
        cc[r] = c2;
        hh[r] = th * oo;
      }
      cst[n] = cc;
#pragma unroll
      for (int r = 0; r < 4; ++r) {
        int row = q * 4 + r, col = 32 * w + 16 * n + rr;
        *(short*)(hb + (par ^ 1) * 8192 + row * 512 + ((col * 2) ^ ((row & 7) << 4))) =
            (short)f2bf(hh[r]);
      }
    }
    __syncthreads();
    par ^= 1;
#pragma unroll
    for (int tt = 0; tt < 8; ++tt) xpc[tt] = xpn[tt];
  }

  if (!last) {
#pragma unroll
    for (int n = 0; n < 2; ++n) {
      *(f32x4*)(state_c + ((size_t)(gb * 8 + w) * 2 + n) * 256 + lane * 4) = cst[n];
      short4_t hs;
#pragma unroll
      for (int r = 0; r < 4; ++r) {
        int row = q * 4 + r, col = 32 * w + 16 * n + rr;
        hs[r] = *(const short*)(hb + par * 8192 + row * 512 + ((col * 2) ^ ((row & 7) << 4)));
      }
      *(short4_t*)(state_h + ((size_t)(gb * 8 + w) * 2 + n) * 256 + lane * 4) = hs;
    }
  } else {
    // final projection: p = h_T @ w_ph + b_p ; wave w -> output col tile w
    float bias = b_p[w * 16 + rr];
    f32x4 po = {bias, bias, bias, bias};
#pragma unroll
    for (int kk = 0; kk < 8; ++kk) {
      short8 a = *(const short8*)(hb + par * 8192 + rr * 512 + ((kk * 64 + q * 16) ^ ((rr & 7) << 4)));
      short8 b = *(const short8*)(pwph + ((size_t)w * 8 + kk) * 512 + lane * 8);
      po = mfma16(a, b, po);
    }
#pragma unroll
    for (int r = 0; r < 4; ++r)
      out[(size_t)(gb * 16 + q * 4 + r) * 128 + w * 16 + rr] = po[r];
  }
}

// ---------------------------------------------------------------------------
extern "C" void kernel_launch(void* const* d_in, const int* in_sizes, int n_in,
                              void* d_out, int out_size, void* d_ws, size_t ws_size,
                              hipStream_t stream) {
  const float* x    = (const float*)d_in[0];
  const float* w_gx = (const float*)d_in[1];
  const float* w_gh = (const float*)d_in[2];
  const float* b_g  = (const float*)d_in[3];
  const float* w_ix = (const float*)d_in[4];
  const float* w_ih = (const float*)d_in[5];
  const float* b_i  = (const float*)d_in[6];
  const float* w_fx = (const float*)d_in[7];
  const float* w_fh = (const float*)d_in[8];
  const float* b_f  = (const float*)d_in[9];
  const float* w_ox = (const float*)d_in[10];
  const float* w_oh = (const float*)d_in[11];
  const float* b_o  = (const float*)d_in[12];
  const float* w_ph = (const float*)d_in[13];
  const float* b_p  = (const float*)d_in[14];

  char* ws = (char*)d_ws;
  short* pwh  = (short*)(ws);            // 524288 B
  short* pwx  = (short*)(ws + 524288);   // 262144 B
  short* pwph = (short*)(ws + 786432);   // 65536 B
  float* bsc  = (float*)(ws + 851968);   // 4096 B
  float* stc  = (float*)(ws + 856064);   // 131072 B
  short* sth  = (short*)(ws + 987136);   // 65536 B
  short* xp   = (short*)(ws + 1052672);  // Tc * 262144 B

  size_t avail = (ws_size > 1052672) ? (ws_size - 1052672) : 0;
  int Tc = 1024;
  while (Tc > 1 && (size_t)Tc * 262144 > avail) Tc >>= 1;

  pack_kernel<<<1668, 256, 0, stream>>>(w_gx, w_gh, b_g, w_ix, w_ih, b_i,
                                        w_fx, w_fh, b_f, w_ox, w_oh, b_o,
                                        w_ph, pwh, pwx, pwph, bsc);
  for (int t0 = 0; t0 < 1024; t0 += Tc) {
    xproj_kernel<<<dim3(Tc, 8), 256, 0, stream>>>(x, pwx, bsc, xp, t0);
    rec_kernel<<<dim3(8), 512, 0, stream>>>(pwh, xp, pwph, b_p, stc, sth,
                                            (float*)d_out, Tc, t0 == 0 ? 1 : 0,
                                            (t0 + Tc == 1024) ? 1 : 0);
  }
  (void)in_sizes; (void)n_in; (void)out_size;
}

// Round 7
// 5992.095 us; speedup vs baseline: 1.1019x; 1.1019x over previous
//
// LSTM_74474732913122 — v5 (retry: rounds 2-6 blocked by harness container disk-full; kernel unchanged)
#include <hip/hip_runtime.h>

typedef __attribute__((ext_vector_type(8))) short short8;
typedef __attribute__((ext_vector_type(4))) short short4_t;
typedef __attribute__((ext_vector_type(4))) float f32x4;

#define LOG2E 1.44269504088896340736f

static __device__ __forceinline__ unsigned short f2bf(float f) {
  unsigned int u = __builtin_bit_cast(unsigned int, f);
  u += 0x7fffu + ((u >> 16) & 1u);
  return (unsigned short)(u >> 16);
}
static __device__ __forceinline__ float bf2f(unsigned short h) {
  return __builtin_bit_cast(float, ((unsigned int)h) << 16);
}
static __device__ __forceinline__ f32x4 mfma16(short8 a, short8 b, f32x4 c) {
  return __builtin_amdgcn_mfma_f32_16x16x32_bf16(a, b, c, 0, 0, 0);
}

// ---------------------------------------------------------------------------
// pack_kernel: fp32 weights -> bf16 MFMA B-fragments, gate scales (log2e /
// 2*log2e) folded in so activations become exp2/rcp only.
// pwh layout: frag tf = ((w*4+g)*2+n)*8+kk  (w=wave 0..7, g=gate, n=subtile,
//             kk=K-step), element = tf*512 + lane*8 + j ; k = 32kk+8q+j,
//             col = 256g + 32w + 16n + rr   (q=lane>>4, rr=lane&15)
// pwx layout: (ct*4+kk)*512 + lane*8 + j ; ct = abs col tile 0..63
// pwph layout: (tc*8+kk)*512 + lane*8 + j ; tc = out col tile 0..7
// ---------------------------------------------------------------------------
__global__ __launch_bounds__(256) void pack_kernel(
    const float* __restrict__ w_gx, const float* __restrict__ w_gh, const float* __restrict__ b_g,
    const float* __restrict__ w_ix, const float* __restrict__ w_ih, const float* __restrict__ b_i,
    const float* __restrict__ w_fx, const float* __restrict__ w_fh, const float* __restrict__ b_f,
    const float* __restrict__ w_ox, const float* __restrict__ w_oh, const float* __restrict__ b_o,
    const float* __restrict__ w_ph,
    short* __restrict__ pwh, short* __restrict__ pwx, short* __restrict__ pwph,
    float* __restrict__ bsc)
{
  int e = blockIdx.x * 256 + threadIdx.x;
  if (e < 262144) {
    int j = e & 7, l = (e >> 3) & 63, tf = e >> 9;
    int kk = tf & 7, n = (tf >> 3) & 1, g = (tf >> 4) & 3, w = tf >> 6;
    int q = l >> 4, rr = l & 15;
    int k = 32 * kk + 8 * q + j;
    int col = 32 * w + 16 * n + rr;
    const float* wh = (g == 0) ? w_gh : (g == 1) ? w_ih : (g == 2) ? w_fh : w_oh;
    float s = (g == 0) ? 2.0f * LOG2E : LOG2E;
    pwh[e] = (short)f2bf(wh[k * 256 + col] * s);
  } else if (e < 262144 + 131072) {
    int e2 = e - 262144;
    int j = e2 & 7, l = (e2 >> 3) & 63, kk = (e2 >> 9) & 3, ct = e2 >> 11;
    int q = l >> 4, rr = l & 15;
    int g = ct >> 4;
    int colg = (ct & 15) * 16 + rr;
    int k = 32 * kk + 8 * q + j;
    const float* wx = (g == 0) ? w_gx : (g == 1) ? w_ix : (g == 2) ? w_fx : w_ox;
    float s = (g == 0) ? 2.0f * LOG2E : LOG2E;
    pwx[e2] = (short)f2bf(wx[k * 256 + colg] * s);
  } else if (e < 262144 + 131072 + 32768) {
    int e3 = e - (262144 + 131072);
    int j = e3 & 7, l = (e3 >> 3) & 63, kk = (e3 >> 9) & 7, tc = e3 >> 12;
    int q = l >> 4, rr = l & 15;
    int k = 32 * kk + 8 * q + j;
    int col = tc * 16 + rr;
    pwph[e3] = (short)f2bf(w_ph[k * 128 + col]);
  } else if (e < 262144 + 131072 + 32768 + 1024) {
    int e4 = e - (262144 + 131072 + 32768);
    int g = e4 >> 8, c = e4 & 255;
    const float* bb = (g == 0) ? b_g : (g == 1) ? b_i : (g == 2) ? b_f : b_o;
    float s = (g == 0) ? 2.0f * LOG2E : LOG2E;
    bsc[e4] = bb[c] * s;
  }
}

// ---------------------------------------------------------------------------
// xproj_kernel: xp[t][b][:] = scale_g * (x[b,t,:] @ w_x + b), written as bf16
// C-fragments in the recurrent kernel's (gb, w, tt) tile order.
// block = 256 thr (4 waves); grid = (Tc, 8)
// ---------------------------------------------------------------------------
__global__ __launch_bounds__(256) void xproj_kernel(
    const float* __restrict__ x, const short* __restrict__ pwx,
    const float* __restrict__ bsc, short* __restrict__ xp, int t0)
{
  __shared__ short xt[2048];  // 16 x 128 bf16, XOR-swizzled rows
  int tid = threadIdx.x;
  int tloc = blockIdx.x, gb = blockIdx.y;
  int t = t0 + tloc;
  {
    int r = tid >> 4, dg = tid & 15;
    const float* src = x + ((size_t)(gb * 16 + r) * 1024 + t) * 128 + dg * 8;
    f32x4 u0 = *(const f32x4*)src;
    f32x4 u1 = *(const f32x4*)(src + 4);
    short8 v;
    v[0] = (short)f2bf(u0[0]); v[1] = (short)f2bf(u0[1]);
    v[2] = (short)f2bf(u0[2]); v[3] = (short)f2bf(u0[3]);
    v[4] = (short)f2bf(u1[0]); v[5] = (short)f2bf(u1[1]);
    v[6] = (short)f2bf(u1[2]); v[7] = (short)f2bf(u1[3]);
    *(short8*)((char*)xt + r * 256 + ((dg * 16) ^ ((r & 7) << 4))) = v;
  }
  __syncthreads();
  int wv = tid >> 6, lane = tid & 63;
  int q = lane >> 4, rr = lane & 15;
  short8 a[4];
#pragma unroll
  for (int kk = 0; kk < 4; ++kk)
    a[kk] = *(const short8*)((const char*)xt + rr * 256 + ((kk * 64 + q * 16) ^ ((rr & 7) << 4)));
#pragma unroll
  for (int i = 0; i < 16; ++i) {
    int ct = wv * 16 + i;
    float bias = bsc[ct * 16 + rr];
    f32x4 acc = {bias, bias, bias, bias};
#pragma unroll
    for (int kk = 0; kk < 4; ++kk) {
      short8 b = *(const short8*)(pwx + (size_t)(ct * 4 + kk) * 512 + lane * 8);
      acc = mfma16(a[kk], b, acc);
    }
    int wrec = (ct >> 1) & 7, tt2 = (ct >> 4) * 2 + (ct & 1);
    short4_t o;
    o[0] = (short)f2bf(acc[0]); o[1] = (short)f2bf(acc[1]);
    o[2] = (short)f2bf(acc[2]); o[3] = (short)f2bf(acc[3]);
    *(short4_t*)(xp + ((size_t)(tloc * 8 + gb) * 64 + wrec * 8 + tt2) * 256 + lane * 4) = o;
  }
}

// ---------------------------------------------------------------------------
// rec_kernel: the serial LSTM loop. grid = 8 WGs (one per 16-row batch group),
// 512 threads (8 waves). Wave w owns h-cols [32w,32w+32): tiles tt = g*2+n.
// Half of w_h (tt 0..3) is PINNED in VGPRs for the whole kernel (128 VGPR) so
// only 256 KB/step streams from L2; streamed tt 4..7 go through a 2-slot
// cyclic prefetch buffer (issue for kk+1 at top of kk body).
// h double-buffered in LDS (XOR swizzle), c in registers (fp32).
// ---------------------------------------------------------------------------
__global__ __launch_bounds__(512, 2) void rec_kernel(
    const short* __restrict__ pwh, const short* __restrict__ xp,
    const short* __restrict__ pwph, const float* __restrict__ b_p,
    float* __restrict__ state_c, short* __restrict__ state_h,
    float* __restrict__ out, int tlen, int first, int last)
{
  __shared__ short hbuf[2][4096];  // 2 x (16 rows x 256 cols) bf16
  int tid = threadIdx.x;
  int gb = blockIdx.x;
  int w = tid >> 6, lane = tid & 63;
  int q = lane >> 4, rr = lane & 15;
  char* hb = (char*)hbuf;

  f32x4 cst[2];
  if (first) {
    f32x4 z = {0.f, 0.f, 0.f, 0.f};
    cst[0] = z; cst[1] = z;
    short8 z8 = {0, 0, 0, 0, 0, 0, 0, 0};
    *(short8*)(hb + tid * 16) = z8;  // 512 thr x 16B = 8192B = hbuf[0]
  } else {
#pragma unroll
    for (int n = 0; n < 2; ++n) {
      cst[n] = *(const f32x4*)(state_c + ((size_t)(gb * 8 + w) * 2 + n) * 256 + lane * 4);
      short4_t hs = *(const short4_t*)(state_h + ((size_t)(gb * 8 + w) * 2 + n) * 256 + lane * 4);
#pragma unroll
      for (int r = 0; r < 4; ++r) {
        int row = q * 4 + r, col = 32 * w + 16 * n + rr;
        *(short*)(hb + row * 512 + ((col * 2) ^ ((row & 7) << 4))) = hs[r];
      }
    }
  }
  __syncthreads();

  // wave's weight slice base (per-lane address)
  const short* wbase = pwh + (size_t)w * 64 * 512 + lane * 8;

  // pinned half of w_h: tiles tt = 0..3 (gates g,i), all 8 K-steps
  short8 pin[4][8];
#pragma unroll
  for (int tt = 0; tt < 4; ++tt)
#pragma unroll
    for (int kk = 0; kk < 8; ++kk)
      pin[tt][kk] = *(const short8*)(wbase + (size_t)(tt * 8 + kk) * 512);

  // streamed half: tiles tt = 4..7, 2-slot cyclic prefetch buffer.
  // slot parity = kk&1; preload kk=0 into slot 0.
  short8 sb[2][4];
#pragma unroll
  for (int s = 0; s < 4; ++s)
    sb[0][s] = *(const short8*)(wbase + (size_t)((s + 4) * 8 + 0) * 512);

  const short* xpbase = xp + (size_t)gb * 64 * 256 + (w * 8) * 256 + lane * 4;
  short4_t xpc[8];
#pragma unroll
  for (int tt = 0; tt < 8; ++tt)
    xpc[tt] = *(const short4_t*)(xpbase + (size_t)tt * 256);

  unsigned par = 0;
  for (int t = 0; t < tlen; ++t) {
    f32x4 acc[8];
#pragma unroll
    for (int tt = 0; tt < 8; ++tt) {
      acc[tt][0] = bf2f((unsigned short)xpc[tt][0]);
      acc[tt][1] = bf2f((unsigned short)xpc[tt][1]);
      acc[tt][2] = bf2f((unsigned short)xpc[tt][2]);
      acc[tt][3] = bf2f((unsigned short)xpc[tt][3]);
    }
    // prefetch next step's xp fragments into the same registers (consumed above)
    {
      int tn = (t + 1 < tlen) ? (t + 1) : t;
      const short* xpn = xp + ((size_t)tn * 8 + gb) * 64 * 256 + (w * 8) * 256 + lane * 4;
#pragma unroll
      for (int tt = 0; tt < 8; ++tt)
        xpc[tt] = *(const short4_t*)(xpn + (size_t)tt * 256);
    }
#pragma unroll
    for (int kk = 0; kk < 8; ++kk) {
      const int kn = (kk + 1) & 7;
      // prefetch streamed fragments for kn (next kk; at kk=7 this is next
      // step's kk=0 — weights are loop-invariant so values are identical)
#pragma unroll
      for (int s = 0; s < 4; ++s)
        sb[kn & 1][s] = *(const short8*)(wbase + (size_t)((s + 4) * 8 + kn) * 512);
      short8 a = *(const short8*)(hb + par * 8192 + rr * 512 + ((kk * 64 + q * 16) ^ ((rr & 7) << 4)));
#pragma unroll
      for (int tt = 0; tt < 4; ++tt)
        acc[tt] = mfma16(a, pin[tt][kk], acc[tt]);
#pragma unroll
      for (int s = 0; s < 4; ++s)
        acc[4 + s] = mfma16(a, sb[kk & 1][s], acc[4 + s]);
    }
#pragma unroll
    for (int n = 0; n < 2; ++n) {
      f32x4 xg = acc[0 + n], xi = acc[2 + n], xf = acc[4 + n], xo = acc[6 + n];
      f32x4 cc = cst[n];
      f32x4 hh;
#pragma unroll
      for (int r = 0; r < 4; ++r) {
        float gg = 2.0f * __builtin_amdgcn_rcpf(1.0f + __builtin_amdgcn_exp2f(-xg[r])) - 1.0f;
        float ii = __builtin_amdgcn_rcpf(1.0f + __builtin_amdgcn_exp2f(-xi[r]));
        float ff = __builtin_amdgcn_rcpf(1.0f + __builtin_amdgcn_exp2f(-xf[r]));
        float oo = __builtin_amdgcn_rcpf(1.0f + __builtin_amdgcn_exp2f(-xo[r]));
        float c2 = gg * ii + cc[r] * ff;
        float th = 2.0f * __builtin_amdgcn_rcpf(1.0f + __builtin_amdgcn_exp2f(-2.0f * LOG2E * c2)) - 1.0f;
        cc[r] = c2;
        hh[r] = th * oo;
      }
      cst[n] = cc;
#pragma unroll
      for (int r = 0; r < 4; ++r) {
        int row = q * 4 + r, col = 32 * w + 16 * n + rr;
        *(short*)(hb + (par ^ 1) * 8192 + row * 512 + ((col * 2) ^ ((row & 7) << 4))) =
            (short)f2bf(hh[r]);
      }
    }
    __syncthreads();
    par ^= 1;
  }

  if (!last) {
#pragma unroll
    for (int n = 0; n < 2; ++n) {
      *(f32x4*)(state_c + ((size_t)(gb * 8 + w) * 2 + n) * 256 + lane * 4) = cst[n];
      short4_t hs;
#pragma unroll
      for (int r = 0; r < 4; ++r) {
        int row = q * 4 + r, col = 32 * w + 16 * n + rr;
        hs[r] = *(const short*)(hb + par * 8192 + row * 512 + ((col * 2) ^ ((row & 7) << 4)));
      }
      *(short4_t*)(state_h + ((size_t)(gb * 8 + w) * 2 + n) * 256 + lane * 4) = hs;
    }
  } else {
    // final projection: p = h_T @ w_ph + b_p ; wave w -> output col tile w
    float bias = b_p[w * 16 + rr];
    f32x4 po = {bias, bias, bias, bias};
#pragma unroll
    for (int kk = 0; kk < 8; ++kk) {
      short8 a = *(const short8*)(hb + par * 8192 + rr * 512 + ((kk * 64 + q * 16) ^ ((rr & 7) << 4)));
      short8 b = *(const short8*)(pwph + (size_t)(w * 8 + kk) * 512 + lane * 8);
      po = mfma16(a, b, po);
    }
#pragma unroll
    for (int r = 0; r < 4; ++r)
      out[(size_t)(gb * 16 + q * 4 + r) * 128 + w * 16 + rr] = po[r];
  }
}

// ---------------------------------------------------------------------------
extern "C" void kernel_launch(void* const* d_in, const int* in_sizes, int n_in,
                              void* d_out, int out_size, void* d_ws, size_t ws_size,
                              hipStream_t stream) {
  const float* x    = (const float*)d_in[0];
  const float* w_gx = (const float*)d_in[1];
  const float* w_gh = (const float*)d_in[2];
  const float* b_g  = (const float*)d_in[3];
  const float* w_ix = (const float*)d_in[4];
  const float* w_ih = (const float*)d_in[5];
  const float* b_i  = (const float*)d_in[6];
  const float* w_fx = (const float*)d_in[7];
  const float* w_fh = (const float*)d_in[8];
  const float* b_f  = (const float*)d_in[9];
  const float* w_ox = (const float*)d_in[10];
  const float* w_oh = (const float*)d_in[11];
  const float* b_o  = (const float*)d_in[12];
  const float* w_ph = (const float*)d_in[13];
  const float* b_p  = (const float*)d_in[14];

  char* ws = (char*)d_ws;
  short* pwh  = (short*)(ws);            // 524288 B
  short* pwx  = (short*)(ws + 524288);   // 262144 B
  short* pwph = (short*)(ws + 786432);   // 65536 B
  float* bsc  = (float*)(ws + 851968);   // 4096 B
  float* stc  = (float*)(ws + 856064);   // 131072 B
  short* sth  = (short*)(ws + 987136);   // 65536 B
  short* xp   = (short*)(ws + 1052672);  // Tc * 262144 B

  size_t avail = (ws_size > 1052672) ? (ws_size - 1052672) : 0;
  int Tc = 1024;
  while (Tc > 1 && (size_t)Tc * 262144 > avail) Tc >>= 1;

  pack_kernel<<<1668, 256, 0, stream>>>(w_gx, w_gh, b_g, w_ix, w_ih, b_i,
                                        w_fx, w_fh, b_f, w_ox, w_oh, b_o,
                                        w_ph, pwh, pwx, pwph, bsc);
  for (int t0 = 0; t0 < 1024; t0 += Tc) {
    xproj_kernel<<<dim3(Tc, 8), 256, 0, stream>>>(x, pwx, bsc, xp, t0);
    rec_kernel<<<dim3(8), 512, 0, stream>>>(pwh, xp, pwph, b_p, stc, sth,
                                            (float*)d_out, Tc, t0 == 0 ? 1 : 0,
                                            (t0 + Tc == 1024) ? 1 : 0);
  }
  (void)in_sizes; (void)n_in; (void)out_size;
}

// Round 9
// 2781.862 us; speedup vs baseline: 2.3734x; 2.1540x over previous
//
// LSTM_74474732913122 — v7 (identical to v6; R8 was an environmental disk-full compile failure)
#include <hip/hip_runtime.h>

typedef __attribute__((ext_vector_type(8))) short short8;
typedef __attribute__((ext_vector_type(4))) short short4_t;
typedef __attribute__((ext_vector_type(4))) float f32x4;

#define LOG2E 1.44269504088896340736f

static __device__ __forceinline__ unsigned short f2bf(float f) {
  unsigned int u = __builtin_bit_cast(unsigned int, f);
  u += 0x7fffu + ((u >> 16) & 1u);
  return (unsigned short)(u >> 16);
}
static __device__ __forceinline__ float bf2f(unsigned short h) {
  return __builtin_bit_cast(float, ((unsigned int)h) << 16);
}
static __device__ __forceinline__ f32x4 mfma16(short8 a, short8 b, f32x4 c) {
  return __builtin_amdgcn_mfma_f32_16x16x32_bf16(a, b, c, 0, 0, 0);
}
static __device__ __forceinline__ f32x4 cvt4(short4_t v) {
  f32x4 o;
  o[0] = bf2f((unsigned short)v[0]); o[1] = bf2f((unsigned short)v[1]);
  o[2] = bf2f((unsigned short)v[2]); o[3] = bf2f((unsigned short)v[3]);
  return o;
}
static __device__ __forceinline__ f32x4 sig4(f32x4 v) {  // input pre-scaled by log2e
  f32x4 o;
#pragma unroll
  for (int r = 0; r < 4; ++r)
    o[r] = __builtin_amdgcn_rcpf(1.0f + __builtin_amdgcn_exp2f(-v[r]));
  return o;
}
static __device__ __forceinline__ f32x4 tanh4(f32x4 v) {  // input pre-scaled by 2*log2e
  f32x4 o;
#pragma unroll
  for (int r = 0; r < 4; ++r)
    o[r] = 2.0f * __builtin_amdgcn_rcpf(1.0f + __builtin_amdgcn_exp2f(-v[r])) - 1.0f;
  return o;
}

// ---------------------------------------------------------------------------
// pack_kernel: fp32 weights -> bf16 MFMA B-fragments, gate scales (log2e /
// 2*log2e) folded in. Layouts:
// pwh:  frag tf = (w*8 + tt)*8 + kk, tt = g*2+n ; elem = tf*512 + lane*8 + j
// pwx:  (ct*4+kk)*512 + lane*8 + j
// pwph: (tc*8+kk)*512 + lane*8 + j
// ---------------------------------------------------------------------------
__global__ __launch_bounds__(256) void pack_kernel(
    const float* __restrict__ w_gx, const float* __restrict__ w_gh, const float* __restrict__ b_g,
    const float* __restrict__ w_ix, const float* __restrict__ w_ih, const float* __restrict__ b_i,
    const float* __restrict__ w_fx, const float* __restrict__ w_fh, const float* __restrict__ b_f,
    const float* __restrict__ w_ox, const float* __restrict__ w_oh, const float* __restrict__ b_o,
    const float* __restrict__ w_ph,
    short* __restrict__ pwh, short* __restrict__ pwx, short* __restrict__ pwph,
    float* __restrict__ bsc)
{
  int e = blockIdx.x * 256 + threadIdx.x;
  if (e < 262144) {
    int j = e & 7, l = (e >> 3) & 63, tf = e >> 9;
    int kk = tf & 7, n = (tf >> 3) & 1, g = (tf >> 4) & 3, w = tf >> 6;
    int q = l >> 4, rr = l & 15;
    int k = 32 * kk + 8 * q + j;
    int col = 32 * w + 16 * n + rr;
    const float* wh = (g == 0) ? w_gh : (g == 1) ? w_ih : (g == 2) ? w_fh : w_oh;
    float s = (g == 0) ? 2.0f * LOG2E : LOG2E;
    pwh[e] = (short)f2bf(wh[k * 256 + col] * s);
  } else if (e < 262144 + 131072) {
    int e2 = e - 262144;
    int j = e2 & 7, l = (e2 >> 3) & 63, kk = (e2 >> 9) & 3, ct = e2 >> 11;
    int q = l >> 4, rr = l & 15;
    int g = ct >> 4;
    int colg = (ct & 15) * 16 + rr;
    int k = 32 * kk + 8 * q + j;
    const float* wx = (g == 0) ? w_gx : (g == 1) ? w_ix : (g == 2) ? w_fx : w_ox;
    float s = (g == 0) ? 2.0f * LOG2E : LOG2E;
    pwx[e2] = (short)f2bf(wx[k * 256 + colg] * s);
  } else if (e < 262144 + 131072 + 32768) {
    int e3 = e - (262144 + 131072);
    int j = e3 & 7, l = (e3 >> 3) & 63, kk = (e3 >> 9) & 7, tc = e3 >> 12;
    int q = l >> 4, rr = l & 15;
    int k = 32 * kk + 8 * q + j;
    int col = tc * 16 + rr;
    pwph[e3] = (short)f2bf(w_ph[k * 128 + col]);
  } else if (e < 262144 + 131072 + 32768 + 1024) {
    int e4 = e - (262144 + 131072 + 32768);
    int g = e4 >> 8, c = e4 & 255;
    const float* bb = (g == 0) ? b_g : (g == 1) ? b_i : (g == 2) ? b_f : b_o;
    float s = (g == 0) ? 2.0f * LOG2E : LOG2E;
    bsc[e4] = bb[c] * s;
  }
}

// ---------------------------------------------------------------------------
// xproj_kernel: unchanged.
// ---------------------------------------------------------------------------
__global__ __launch_bounds__(256) void xproj_kernel(
    const float* __restrict__ x, const short* __restrict__ pwx,
    const float* __restrict__ bsc, short* __restrict__ xp, int t0)
{
  __shared__ short xt[2048];
  int tid = threadIdx.x;
  int tloc = blockIdx.x, gb = blockIdx.y;
  int t = t0 + tloc;
  {
    int r = tid >> 4, dg = tid & 15;
    const float* src = x + ((size_t)(gb * 16 + r) * 1024 + t) * 128 + dg * 8;
    f32x4 u0 = *(const f32x4*)src;
    f32x4 u1 = *(const f32x4*)(src + 4);
    short8 v;
    v[0] = (short)f2bf(u0[0]); v[1] = (short)f2bf(u0[1]);
    v[2] = (short)f2bf(u0[2]); v[3] = (short)f2bf(u0[3]);
    v[4] = (short)f2bf(u1[0]); v[5] = (short)f2bf(u1[1]);
    v[6] = (short)f2bf(u1[2]); v[7] = (short)f2bf(u1[3]);
    *(short8*)((char*)xt + r * 256 + ((dg * 16) ^ ((r & 7) << 4))) = v;
  }
  __syncthreads();
  int wv = tid >> 6, lane = tid & 63;
  int q = lane >> 4, rr = lane & 15;
  short8 a[4];
#pragma unroll
  for (int kk = 0; kk < 4; ++kk)
    a[kk] = *(const short8*)((const char*)xt + rr * 256 + ((kk * 64 + q * 16) ^ ((rr & 7) << 4)));
#pragma unroll
  for (int i = 0; i < 16; ++i) {
    int ct = wv * 16 + i;
    float bias = bsc[ct * 16 + rr];
    f32x4 acc = {bias, bias, bias, bias};
#pragma unroll
    for (int kk = 0; kk < 4; ++kk) {
      short8 b = *(const short8*)(pwx + (size_t)(ct * 4 + kk) * 512 + lane * 8);
      acc = mfma16(a[kk], b, acc);
    }
    int wrec = (ct >> 1) & 7, tt2 = (ct >> 4) * 2 + (ct & 1);
    short4_t o;
    o[0] = (short)f2bf(acc[0]); o[1] = (short)f2bf(acc[1]);
    o[2] = (short)f2bf(acc[2]); o[3] = (short)f2bf(acc[3]);
    *(short4_t*)(xp + ((size_t)(tloc * 8 + gb) * 64 + wrec * 8 + tt2) * 256 + lane * 4) = o;
  }
}

// ---------------------------------------------------------------------------
// rec_kernel v7 (= v6). grid = 8 WGs x 512 thr (8 waves). Per step, per wave:
//   a[0..8) preloaded from LDS h-buffer once;
//   gate pairs processed tile-major G(LDS wts) -> I -> F -> O (streamed wts,
//   two 64-VGPR pair-slots with >=1-pair prefetch distance);
//   each pair's activations interleave with the next pair's MFMAs.
// LDS: hbuf 16 KB + G-weights 128 KB = 144 KB.
// ---------------------------------------------------------------------------
__global__ __launch_bounds__(512, 2) void rec_kernel(
    const short* __restrict__ pwh, const short* __restrict__ xp,
    const short* __restrict__ pwph, const float* __restrict__ b_p,
    float* __restrict__ state_c, short* __restrict__ state_h,
    float* __restrict__ out, int tlen, int first, int last)
{
  __shared__ char lds[147456];  // [0,16384): hbuf[2][8192B]; [16384,...): G-weights
  int tid = threadIdx.x;
  int gb = blockIdx.x;
  int w = tid >> 6, lane = tid & 63;
  int q = lane >> 4, rr = lane & 15;
  char* hb = lds;

  f32x4 cst0, cst1;
  if (first) {
    f32x4 z = {0.f, 0.f, 0.f, 0.f};
    cst0 = z; cst1 = z;
    short8 z8 = {0, 0, 0, 0, 0, 0, 0, 0};
    *(short8*)(hb + tid * 16) = z8;  // zero hbuf[0]
  } else {
    cst0 = *(const f32x4*)(state_c + ((size_t)(gb * 8 + w) * 2 + 0) * 256 + lane * 4);
    cst1 = *(const f32x4*)(state_c + ((size_t)(gb * 8 + w) * 2 + 1) * 256 + lane * 4);
#pragma unroll
    for (int n = 0; n < 2; ++n) {
      short4_t hs = *(const short4_t*)(state_h + ((size_t)(gb * 8 + w) * 2 + n) * 256 + lane * 4);
#pragma unroll
      for (int r = 0; r < 4; ++r) {
        int row = q * 4 + r, col = 32 * w + 16 * n + rr;
        *(short*)(hb + row * 512 + ((col * 2) ^ ((row & 7) << 4))) = hs[r];
      }
    }
  }
  // fill G-weight LDS block (tiles tt=0,1, all kk, every wave): 128 KB once.
  {
    int lf = tid >> 2, part = tid & 3;            // lf = (ww*2+tt)*8+kk
    int ww = lf >> 4, tt = (lf >> 3) & 1, kk = lf & 7;
    const short* src = pwh + (size_t)((ww * 8 + tt) * 8 + kk) * 512 + part * 128;
    short8* dst = (short8*)(lds + 16384 + (size_t)lf * 1024 + part * 256);
#pragma unroll
    for (int i = 0; i < 16; ++i) dst[i] = ((const short8*)src)[i];
  }
  __syncthreads();

  const short* wbase = pwh + (size_t)w * 64 * 512 + lane * 8;   // streamed weights
  const char* gw = lds + 16384 + (size_t)(w * 2) * 8192 + lane * 16;  // this wave's G wts

  const short* xpbase = xp + (size_t)gb * 64 * 256 + (w * 8) * 256 + lane * 4;
  short4_t xpc[8];
#pragma unroll
  for (int tt = 0; tt < 8; ++tt)
    xpc[tt] = *(const short4_t*)(xpbase + (size_t)tt * 256);

  unsigned par = 0;
  for (int t = 0; t < tlen; ++t) {
    // --- step top: a-preload, slotA <- tiles(2,3), next-step xp ---
    short8 a[8];
#pragma unroll
    for (int kk = 0; kk < 8; ++kk)
      a[kk] = *(const short8*)(hb + par * 8192 + rr * 512 + ((kk * 64 + q * 16) ^ ((rr & 7) << 4)));
    short8 sA[2][8];
#pragma unroll
    for (int t2 = 0; t2 < 2; ++t2)
#pragma unroll
      for (int kk = 0; kk < 8; ++kk)
        sA[t2][kk] = *(const short8*)(wbase + (size_t)((t2 + 2) * 8 + kk) * 512);
    short4_t xpn[8];
    {
      int tn = (t + 1 < tlen) ? (t + 1) : t;
      const short* xpnb = xp + ((size_t)tn * 8 + gb) * 64 * 256 + (w * 8) * 256 + lane * 4;
#pragma unroll
      for (int tt = 0; tt < 8; ++tt)
        xpn[tt] = *(const short4_t*)(xpnb + (size_t)tt * 256);
    }

    // --- G pair (weights from LDS) ---
    f32x4 aG0 = cvt4(xpc[0]), aG1 = cvt4(xpc[1]);
#pragma unroll
    for (int kk = 0; kk < 8; ++kk) {
      short8 w0 = *(const short8*)(gw + (size_t)kk * 1024);
      short8 w1 = *(const short8*)(gw + 8192 + (size_t)kk * 1024);
      aG0 = mfma16(a[kk], w0, aG0);
      aG1 = mfma16(a[kk], w1, aG1);
    }
    // issue slotB <- tiles(4,5)
    short8 sB[2][8];
#pragma unroll
    for (int t2 = 0; t2 < 2; ++t2)
#pragma unroll
      for (int kk = 0; kk < 8; ++kk)
        sB[t2][kk] = *(const short8*)(wbase + (size_t)((t2 + 4) * 8 + kk) * 512);
    f32x4 tg0 = tanh4(aG0), tg1 = tanh4(aG1);

    // --- I pair (slotA) ---
    f32x4 aI0 = cvt4(xpc[2]), aI1 = cvt4(xpc[3]);
#pragma unroll
    for (int kk = 0; kk < 8; ++kk) {
      aI0 = mfma16(a[kk], sA[0][kk], aI0);
      aI1 = mfma16(a[kk], sA[1][kk], aI1);
    }
    // re-issue slotA <- tiles(6,7)
#pragma unroll
    for (int t2 = 0; t2 < 2; ++t2)
#pragma unroll
      for (int kk = 0; kk < 8; ++kk)
        sA[t2][kk] = *(const short8*)(wbase + (size_t)((t2 + 6) * 8 + kk) * 512);
    f32x4 p0, p1;
    {
      f32x4 si0 = sig4(aI0), si1 = sig4(aI1);
#pragma unroll
      for (int r = 0; r < 4; ++r) { p0[r] = tg0[r] * si0[r]; p1[r] = tg1[r] * si1[r]; }
    }

    // --- F pair (slotB) ---
    f32x4 aF0 = cvt4(xpc[4]), aF1 = cvt4(xpc[5]);
#pragma unroll
    for (int kk = 0; kk < 8; ++kk) {
      aF0 = mfma16(a[kk], sB[0][kk], aF0);
      aF1 = mfma16(a[kk], sB[1][kk], aF1);
    }
    {
      f32x4 sf0 = sig4(aF0), sf1 = sig4(aF1);
#pragma unroll
      for (int r = 0; r < 4; ++r) {
        cst0[r] = p0[r] + cst0[r] * sf0[r];
        cst1[r] = p1[r] + cst1[r] * sf1[r];
      }
    }

    // --- O pair (slotA, 2nd fill) ---
    f32x4 aO0 = cvt4(xpc[6]), aO1 = cvt4(xpc[7]);
#pragma unroll
    for (int kk = 0; kk < 8; ++kk) {
      aO0 = mfma16(a[kk], sA[0][kk], aO0);
      aO1 = mfma16(a[kk], sA[1][kk], aO1);
    }
    {
      f32x4 so0 = sig4(aO0), so1 = sig4(aO1);
      f32x4 c2s0, c2s1;
#pragma unroll
      for (int r = 0; r < 4; ++r) { c2s0[r] = 2.0f * LOG2E * cst0[r]; c2s1[r] = 2.0f * LOG2E * cst1[r]; }
      f32x4 th0 = tanh4(c2s0), th1 = tanh4(c2s1);
#pragma unroll
      for (int r = 0; r < 4; ++r) {
        int row = q * 4 + r;
        int col0 = 32 * w + rr, col1 = 32 * w + 16 + rr;
        *(short*)(hb + (par ^ 1) * 8192 + row * 512 + ((col0 * 2) ^ ((row & 7) << 4))) =
            (short)f2bf(th0[r] * so0[r]);
        *(short*)(hb + (par ^ 1) * 8192 + row * 512 + ((col1 * 2) ^ ((row & 7) << 4))) =
            (short)f2bf(th1[r] * so1[r]);
      }
    }
    __syncthreads();
    par ^= 1;
#pragma unroll
    for (int tt = 0; tt < 8; ++tt) xpc[tt] = xpn[tt];
  }

  if (!last) {
    *(f32x4*)(state_c + ((size_t)(gb * 8 + w) * 2 + 0) * 256 + lane * 4) = cst0;
    *(f32x4*)(state_c + ((size_t)(gb * 8 + w) * 2 + 1) * 256 + lane * 4) = cst1;
#pragma unroll
    for (int n = 0; n < 2; ++n) {
      short4_t hs;
#pragma unroll
      for (int r = 0; r < 4; ++r) {
        int row = q * 4 + r, col = 32 * w + 16 * n + rr;
        hs[r] = *(const short*)(hb + par * 8192 + row * 512 + ((col * 2) ^ ((row & 7) << 4)));
      }
      *(short4_t*)(state_h + ((size_t)(gb * 8 + w) * 2 + n) * 256 + lane * 4) = hs;
    }
  } else {
    float bias = b_p[w * 16 + rr];
    f32x4 po = {bias, bias, bias, bias};
#pragma unroll
    for (int kk = 0; kk < 8; ++kk) {
      short8 a2 = *(const short8*)(hb + par * 8192 + rr * 512 + ((kk * 64 + q * 16) ^ ((rr & 7) << 4)));
      short8 b = *(const short8*)(pwph + (size_t)(w * 8 + kk) * 512 + lane * 8);
      po = mfma16(a2, b, po);
    }
#pragma unroll
    for (int r = 0; r < 4; ++r)
      out[(size_t)(gb * 16 + q * 4 + r) * 128 + w * 16 + rr] = po[r];
  }
}

// ---------------------------------------------------------------------------
extern "C" void kernel_launch(void* const* d_in, const int* in_sizes, int n_in,
                              void* d_out, int out_size, void* d_ws, size_t ws_size,
                              hipStream_t stream) {
  const float* x    = (const float*)d_in[0];
  const float* w_gx = (const float*)d_in[1];
  const float* w_gh = (const float*)d_in[2];
  const float* b_g  = (const float*)d_in[3];
  const float* w_ix = (const float*)d_in[4];
  const float* w_ih = (const float*)d_in[5];
  const float* b_i  = (const float*)d_in[6];
  const float* w_fx = (const float*)d_in[7];
  const float* w_fh = (const float*)d_in[8];
  const float* b_f  = (const float*)d_in[9];
  const float* w_ox = (const float*)d_in[10];
  const float* w_oh = (const float*)d_in[11];
  const float* b_o  = (const float*)d_in[12];
  const float* w_ph = (const float*)d_in[13];
  const float* b_p  = (const float*)d_in[14];

  char* ws = (char*)d_ws;
  short* pwh  = (short*)(ws);            // 524288 B
  short* pwx  = (short*)(ws + 524288);   // 262144 B
  short* pwph = (short*)(ws + 786432);   // 65536 B
  float* bsc  = (float*)(ws + 851968);   // 4096 B
  float* stc  = (float*)(ws + 856064);   // 131072 B
  short* sth  = (short*)(ws + 987136);   // 65536 B
  short* xp   = (short*)(ws + 1052672);  // Tc * 262144 B

  size_t avail = (ws_size > 1052672) ? (ws_size - 1052672) : 0;
  int Tc = 1024;
  while (Tc > 1 && (size_t)Tc * 262144 > avail) Tc >>= 1;

  pack_kernel<<<1668, 256, 0, stream>>>(w_gx, w_gh, b_g, w_ix, w_ih, b_i,
                                        w_fx, w_fh, b_f, w_ox, w_oh, b_o,
                                        w_ph, pwh, pwx, pwph, bsc);
  for (int t0 = 0; t0 < 1024; t0 += Tc) {
    xproj_kernel<<<dim3(Tc, 8), 256, 0, stream>>>(x, pwx, bsc, xp, t0);
    rec_kernel<<<dim3(8), 512, 0, stream>>>(pwh, xp, pwph, b_p, stc, sth,
                                            (float*)d_out, Tc, t0 == 0 ? 1 : 0,
                                            (t0 + Tc == 1024) ? 1 : 0);
  }
  (void)in_sizes; (void)n_in; (void)out_size;
}